// Round 9
// baseline (578.015 us; speedup 1.0000x reference)
//
#include <hip/hip_runtime.h>
#include <math.h>

#define N_INST 2048
#define N_REL  1024
#define FEAT   50176   // 256*14*14
#define FEAT4  12544   // FEAT/4
#define IPB    4       // instances per block
#define NBLK   (N_INST / IPB)   // 512 blocks

// ---------------- kernel 1: fused flag-scan + per-instance dual dots ----
// dA[n] = mf[n] . w[0:FEAT],  dB[n] = mf[n] . w[FEAT:2*FEAT]
// Each block owns 4 consecutive instances. It first scans `pairs` (8 KB,
// L2-resident) to find which of its instances are referenced, then streams
// w once (reused 4x from L1/L2) against up to 4 mask rows. Unused rows are
// skipped via block-uniform branches.
__global__ __launch_bounds__(256) void dual_dot_fused(
    const float* __restrict__ mf, const float* __restrict__ w,
    const int* __restrict__ pairs, float* __restrict__ dA, float* __restrict__ dB)
{
    const int n0 = blockIdx.x * IPB;

    // --- which of n0..n0+3 appear anywhere in pairs? (bitmask) ---
    unsigned um = 0;
    for (int t = threadIdx.x; t < 2 * N_REL; t += 256) {
        unsigned v = (unsigned)(pairs[t] - n0);
        if (v < IPB) um |= 1u << v;
    }
    for (int off = 32; off; off >>= 1) um |= __shfl_xor(um, off, 64);
    __shared__ unsigned smask[4];
    if ((threadIdx.x & 63) == 0) smask[threadIdx.x >> 6] = um;
    __syncthreads();
    um = smask[0] | smask[1] | smask[2] | smask[3];
    if (um == 0) return;

    const float4* __restrict__ wA = (const float4*)w;
    const float4* __restrict__ wB = (const float4*)(w + FEAT);
    const float4* __restrict__ r  = (const float4*)(mf + (size_t)n0 * FEAT);

    float sA0 = 0.f, sB0 = 0.f, sA1 = 0.f, sB1 = 0.f;
    float sA2 = 0.f, sB2 = 0.f, sA3 = 0.f, sB3 = 0.f;
    for (int k = threadIdx.x; k < FEAT4; k += 256) {
        float4 a = wA[k];
        float4 b = wB[k];
        if (um & 1u) {
            float4 v = r[k];
            sA0 += v.x*a.x + v.y*a.y + v.z*a.z + v.w*a.w;
            sB0 += v.x*b.x + v.y*b.y + v.z*b.z + v.w*b.w;
        }
        if (um & 2u) {
            float4 v = r[k + FEAT4];
            sA1 += v.x*a.x + v.y*a.y + v.z*a.z + v.w*a.w;
            sB1 += v.x*b.x + v.y*b.y + v.z*b.z + v.w*b.w;
        }
        if (um & 4u) {
            float4 v = r[k + 2 * FEAT4];
            sA2 += v.x*a.x + v.y*a.y + v.z*a.z + v.w*a.w;
            sB2 += v.x*b.x + v.y*b.y + v.z*b.z + v.w*b.w;
        }
        if (um & 8u) {
            float4 v = r[k + 3 * FEAT4];
            sA3 += v.x*a.x + v.y*a.y + v.z*a.z + v.w*a.w;
            sB3 += v.x*b.x + v.y*b.y + v.z*b.z + v.w*b.w;
        }
    }

    // wave-level reduction (64 lanes)
    for (int off = 32; off; off >>= 1) {
        sA0 += __shfl_down(sA0, off, 64);  sB0 += __shfl_down(sB0, off, 64);
        sA1 += __shfl_down(sA1, off, 64);  sB1 += __shfl_down(sB1, off, 64);
        sA2 += __shfl_down(sA2, off, 64);  sB2 += __shfl_down(sB2, off, 64);
        sA3 += __shfl_down(sA3, off, 64);  sB3 += __shfl_down(sB3, off, 64);
    }
    __shared__ float red[4][8];
    const int wid = threadIdx.x >> 6;
    if ((threadIdx.x & 63) == 0) {
        red[wid][0] = sA0; red[wid][1] = sB0;
        red[wid][2] = sA1; red[wid][3] = sB1;
        red[wid][4] = sA2; red[wid][5] = sB2;
        red[wid][6] = sA3; red[wid][7] = sB3;
    }
    __syncthreads();
    if (threadIdx.x < 8) {
        const int t = threadIdx.x;
        float x = red[0][t] + red[1][t] + red[2][t] + red[3][t];
        const int inst = n0 + (t >> 1);
        if (um & (1u << (t >> 1))) {
            if (t & 1) dB[inst] = x; else dA[inst] = x;
        }
    }
}

// ---------------- kernel 2: logits -> BCE -> mean -----------------------
__device__ __forceinline__ float softplus_f(float x) {
    // numerically stable softplus(x) = log(1 + e^x)
    return fmaxf(x, 0.f) + log1pf(expf(-fabsf(x)));
}

__global__ __launch_bounds__(1024) void bce_kernel(
    const int* __restrict__ pairs, const float* __restrict__ dA,
    const float* __restrict__ dB, const float* __restrict__ bptr,
    float* __restrict__ out)
{
    const int t = threadIdx.x;               // 0..1023, one pair per thread
    const float bb = bptr[0];
    const int i = pairs[2 * t];
    const int j = pairs[2 * t + 1];
    const float lf = dA[i] + dB[j] + bb;     // target = 1 -> bce = softplus(-x)
    const float lr = dA[j] + dB[i] + bb;     // target = 0 -> bce = softplus(+x)
    float v = softplus_f(-lf) + softplus_f(lr);

    for (int off = 32; off; off >>= 1) v += __shfl_down(v, off, 64);
    __shared__ float red[16];
    if ((t & 63) == 0) red[t >> 6] = v;
    __syncthreads();
    if (t < 16) {
        float x = red[t];
        for (int off = 8; off; off >>= 1) x += __shfl_down(x, off, 16);
        if (t == 0) out[0] = x * (1.0f / (2 * N_REL));
    }
}

extern "C" void kernel_launch(void* const* d_in, const int* in_sizes, int n_in,
                              void* d_out, int out_size, void* d_ws, size_t ws_size,
                              hipStream_t stream) {
    const float* mf    = (const float*)d_in[0];   // (2048, 256, 14, 14) f32
    const int*   pairs = (const int*)d_in[1];     // (1024, 2) int
    const float* w     = (const float*)d_in[2];   // (100352,) f32
    const float* b     = (const float*)d_in[3];   // (1,) f32
    float* out = (float*)d_out;                   // scalar loss

    float* dA = (float*)d_ws;                     // 2048 f32
    float* dB = dA + N_INST;                      // 2048 f32

    dual_dot_fused<<<NBLK, 256, 0, stream>>>(mf, w, pairs, dA, dB);
    bce_kernel<<<1, 1024, 0, stream>>>(pairs, dA, dB, b, out);
}

// Round 11
// 552.862 us; speedup vs baseline: 1.0455x; 1.0455x over previous
//
#include <hip/hip_runtime.h>
#include <math.h>

#define N_INST 2048
#define N_REL  1024
#define FEAT   50176   // 256*14*14
#define FEAT4  12544   // FEAT/4
#define IPB    2       // instances per block
#define NBLK   (N_INST / IPB)   // 1024 blocks

// ---------------- kernel 1: zero the used-instance flags ----------------
__global__ void init_flags_kernel(int* __restrict__ flags) {
    int n = blockIdx.x * blockDim.x + threadIdx.x;
    if (n < N_INST) flags[n] = 0;
}

// ---------------- kernel 2: mark instances referenced by any pair -------
__global__ void mark_used_kernel(const int* __restrict__ pairs, int* __restrict__ flags) {
    int t = blockIdx.x * blockDim.x + threadIdx.x;
    if (t < 2 * N_REL) flags[pairs[t]] = 1;   // same-value stores, no atomic needed
}

// ---------------- kernel 3: per-instance dual dot products --------------
// dA[n] = mf[n] . w[0:FEAT],  dB[n] = mf[n] . w[FEAT:2*FEAT]
// One block handles IPB=2 consecutive instances so each w element fetched
// from L2 is reused for 2 mask rows. Unused instances are skipped entirely
// (block-uniform branches; flags identical across the block).
// Measured (round 2): this structure = ~50 us of a 554 us total; the other
// ~505 us is the harness's 2x 1.644 GB workspace re-poison fills.
// Round 9 measured IPB=4 fused-scan variant at ~70 us -> reverted.
__global__ __launch_bounds__(256) void dual_dot_kernel(
    const float* __restrict__ mf, const float* __restrict__ w,
    const int* __restrict__ flags, float* __restrict__ dA, float* __restrict__ dB)
{
    const int n0 = blockIdx.x * IPB;
    const int used0 = flags[n0];
    const int used1 = flags[n0 + 1];
    if (!(used0 | used1)) return;

    const float4* __restrict__ wA = (const float4*)w;
    const float4* __restrict__ wB = (const float4*)(w + FEAT);
    const float4* __restrict__ r0 = (const float4*)(mf + (size_t)n0 * FEAT);
    const float4* __restrict__ r1 = (const float4*)(mf + (size_t)(n0 + 1) * FEAT);

    float sA0 = 0.f, sB0 = 0.f, sA1 = 0.f, sB1 = 0.f;
    for (int k = threadIdx.x; k < FEAT4; k += 256) {
        float4 a = wA[k];
        float4 b = wB[k];
        if (used0) {
            float4 m = r0[k];
            sA0 += m.x*a.x + m.y*a.y + m.z*a.z + m.w*a.w;
            sB0 += m.x*b.x + m.y*b.y + m.z*b.z + m.w*b.w;
        }
        if (used1) {
            float4 m = r1[k];
            sA1 += m.x*a.x + m.y*a.y + m.z*a.z + m.w*a.w;
            sB1 += m.x*b.x + m.y*b.y + m.z*b.z + m.w*b.w;
        }
    }

    // wave-level reduction (64 lanes)
    for (int off = 32; off; off >>= 1) {
        sA0 += __shfl_down(sA0, off, 64);
        sB0 += __shfl_down(sB0, off, 64);
        sA1 += __shfl_down(sA1, off, 64);
        sB1 += __shfl_down(sB1, off, 64);
    }
    __shared__ float red[4][4];
    const int wid = threadIdx.x >> 6;
    if ((threadIdx.x & 63) == 0) {
        red[wid][0] = sA0; red[wid][1] = sB0;
        red[wid][2] = sA1; red[wid][3] = sB1;
    }
    __syncthreads();
    if (threadIdx.x == 0) {
        float a0 = 0.f, b0 = 0.f, a1 = 0.f, b1 = 0.f;
        for (int q = 0; q < 4; ++q) {
            a0 += red[q][0]; b0 += red[q][1];
            a1 += red[q][2]; b1 += red[q][3];
        }
        if (used0) { dA[n0]     = a0; dB[n0]     = b0; }
        if (used1) { dA[n0 + 1] = a1; dB[n0 + 1] = b1; }
    }
}

// ---------------- kernel 4: logits -> BCE -> mean -----------------------
__device__ __forceinline__ float softplus_f(float x) {
    // numerically stable softplus(x) = log(1 + e^x)
    return fmaxf(x, 0.f) + log1pf(expf(-fabsf(x)));
}

__global__ __launch_bounds__(1024) void bce_kernel(
    const int* __restrict__ pairs, const float* __restrict__ dA,
    const float* __restrict__ dB, const float* __restrict__ bptr,
    float* __restrict__ out)
{
    const int t = threadIdx.x;               // 0..1023, one pair per thread
    const float bb = bptr[0];
    const int i = pairs[2 * t];
    const int j = pairs[2 * t + 1];
    const float lf = dA[i] + dB[j] + bb;     // target = 1 -> bce = softplus(-x)
    const float lr = dA[j] + dB[i] + bb;     // target = 0 -> bce = softplus(+x)
    float v = softplus_f(-lf) + softplus_f(lr);

    for (int off = 32; off; off >>= 1) v += __shfl_down(v, off, 64);
    __shared__ float red[16];
    if ((t & 63) == 0) red[t >> 6] = v;
    __syncthreads();
    if (t < 16) {
        float x = red[t];
        for (int off = 8; off; off >>= 1) x += __shfl_down(x, off, 16);
        if (t == 0) out[0] = x * (1.0f / (2 * N_REL));
    }
}

extern "C" void kernel_launch(void* const* d_in, const int* in_sizes, int n_in,
                              void* d_out, int out_size, void* d_ws, size_t ws_size,
                              hipStream_t stream) {
    const float* mf    = (const float*)d_in[0];   // (2048, 256, 14, 14) f32
    const int*   pairs = (const int*)d_in[1];     // (1024, 2) int
    const float* w     = (const float*)d_in[2];   // (100352,) f32
    const float* b     = (const float*)d_in[3];   // (1,) f32
    float* out = (float*)d_out;                   // scalar loss

    float* dA    = (float*)d_ws;                  // 2048 f32
    float* dB    = dA + N_INST;                   // 2048 f32
    int*   flags = (int*)(dB + N_INST);           // 2048 int

    init_flags_kernel<<<(N_INST + 255) / 256, 256, 0, stream>>>(flags);
    mark_used_kernel<<<(2 * N_REL + 255) / 256, 256, 0, stream>>>(pairs, flags);
    dual_dot_kernel<<<NBLK, 256, 0, stream>>>(mf, w, flags, dA, dB);
    bce_kernel<<<1, 1024, 0, stream>>>(pairs, dA, dB, b, out);
}